// Round 5
// baseline (90.286 us; speedup 1.0000x reference)
//
#include <hip/hip_runtime.h>
#include <hip/hip_bf16.h>

typedef __attribute__((ext_vector_type(8))) short bf16x8;
typedef __attribute__((ext_vector_type(4))) float f32x4;

#define N_PTS   16384
#define C_CH    64
#define K_ADJ   17
#define C_OUT   128
#define N_J     16

// Weights as a pre-swizzled "LDS image": 4 chunks x 64 KB. Chunk c holds
// j in [c*4, c*4+4). Within a chunk, 16B-slot s: row = s>>3 = (j&3)*128 + o,
// c8 = s&7, and the k-slot group stored there is p8 = c8 ^ (row&7) (XOR bank
// swizzle, T2/m173: swizzle on the SOURCE so a linear global_load_lds DMA
// lands the swizzled layout). k-slot p -> channel permutation matches the
// full-line gather mapping (verified R4: passed, absmax 4.9e-4).
__device__ __hip_bfloat16 g_wb[N_J * C_OUT * C_CH];

__global__ __launch_bounds__(256) void prep_weights_k(const float* __restrict__ w) {
    int idx = blockIdx.x * 256 + threadIdx.x;      // 0 .. 131071 exactly
    int S   = idx >> 3, r = idx & 7;               // 16B slot, element within
    int c   = S >> 12, s = S & 4095;               // chunk, slot in chunk
    int row = s >> 3,  c8 = s & 7;
    int p8  = c8 ^ (row & 7);                      // inverse of read-side XOR
    int j   = c * 4 + (row >> 7);
    int o   = row & 127;
    int p   = p8 * 8 + r;
    int hi  = p >> 5, q = p & 31, la = q >> 3, rr = q & 7;
    int ch  = hi * 32 + (rr < 4 ? la * 4 + rr : 16 + la * 4 + (rr - 4));
    g_wb[idx] = __float2bfloat16(w[(o * C_CH + ch) * (K_ADJ - 1) + j]);
}

#define GLOAD(gp, lp) __builtin_amdgcn_global_load_lds(                       \
    (const __attribute__((address_space(1))) void*)(gp),                      \
    (__attribute__((address_space(3))) void*)(lp), 16, 0, 0)

struct PF { float4 v0, v1, v2, v3; };

__device__ __forceinline__ void issue_gather(PF& p, const float* __restrict__ xb,
                                             int row, int lk) {
    // full-line remap: lane reads 16 contiguous B at row*256 + i*64 + lk*16
    const float* gp = xb + (size_t)row * C_CH + lk * 4;
    p.v0 = *(const float4*)(gp +  0);
    p.v1 = *(const float4*)(gp + 16);
    p.v2 = *(const float4*)(gp + 32);
    p.v3 = *(const float4*)(gp + 48);
}

// Block: 512 threads = 8 waves = 128 tokens; each wave computes all 128
// outputs for its 16 tokens (gathers fully dedup'd). Weights stream through
// 2 x 64KB LDS buffers via async global_load_lds; 4 barriers total.
// Grid 256 = 1 block/CU.
__global__ __launch_bounds__(512) void sconv_k(
    const float* __restrict__ x,
    const int*   __restrict__ adj,
    float*       __restrict__ out)
{
    __shared__ __hip_bfloat16 lds_w[2][4 * C_OUT * C_CH];   // 2 x 64 KB

    // XCD swizzle (256 blocks): XCDs 0..3 -> batch 0, XCDs 4..7 -> batch 1,
    // so each XCD's 4 MB L2 holds exactly its batch's 4 MB x slice.
    const int pblk = blockIdx.x;
    const int g8   = pblk & 7;
    const int b    = g8 >> 2;
    const int slot = ((pblk >> 3) << 2) | (g8 & 3);          // 0..127 per batch

    const int tid  = threadIdx.x;
    const int lane = tid & 63;
    const int w8   = tid >> 6;                               // wave 0..7
    const int lrow = lane & 15;                              // token in group
    const int lk   = lane >> 4;                              // k-slot group

    const int n = slot * 128 + w8 * 16 + lrow;               // this lane's token

    const float* __restrict__ xb   = x   + (size_t)b * N_PTS * C_CH;
    const int*   __restrict__ adjb = adj + (size_t)b * N_PTS * K_ADJ;
    float*       __restrict__ ob   = out + (size_t)b * C_OUT * N_PTS;

    // ---- async fills for chunks 0 and 1 (issued before everything) ----
    #pragma unroll
    for (int i = 0; i < 8; ++i) {
        const int lo = (w8 * 8 + i) * 512;                   // elements, wave-uniform
        GLOAD(g_wb +     lo + lane * 8, &lds_w[0][lo]);
        GLOAD(g_wb + 32768 + lo + lane * 8, &lds_w[1][lo]);
    }

    // center row (full-line remap: d[i*4+q] = channel i*16 + lk*4 + q)
    float ctr[16];
    {
        const float* rp = xb + (size_t)n * C_CH + lk * 4;
        #pragma unroll
        for (int i = 0; i < 4; ++i) {
            float4 v = *(const float4*)(rp + i * 16);
            ctr[i*4+0]=v.x; ctr[i*4+1]=v.y; ctr[i*4+2]=v.z; ctr[i*4+3]=v.w;
        }
    }

    int aidx[N_J];
    {
        const int base = n * K_ADJ + 1;
        #pragma unroll
        for (int j = 0; j < N_J; ++j) aidx[j] = adjb[base + j];
    }

    f32x4 maxacc[8];
    #pragma unroll
    for (int of = 0; of < 8; ++of) maxacc[of] = f32x4{0.f, 0.f, 0.f, 0.f};

    // gather prefetch depth 2 (named bufs -> all-static indexing, rule #20)
    PF pf0, pf1;
    issue_gather(pf0, xb, aidx[0], lk);
    issue_gather(pf1, xb, aidx[1], lk);

    __syncthreads();   // vmcnt(0)+barrier: chunks 0,1 resident; pf0/pf1 ready

    const int sw = lrow & 7;

    #pragma unroll
    for (int c = 0; c < 4; ++c) {
        const __hip_bfloat16* buf = lds_w[c & 1];

        #pragma unroll
        for (int jj = 0; jj < 4; ++jj) {
            const int j = c * 4 + jj;

            float d[16];
            {
                const PF& p = (j & 1) ? pf1 : pf0;
                d[0] =p.v0.x; d[1] =p.v0.y; d[2] =p.v0.z; d[3] =p.v0.w;
                d[4] =p.v1.x; d[5] =p.v1.y; d[6] =p.v1.z; d[7] =p.v1.w;
                d[8] =p.v2.x; d[9] =p.v2.y; d[10]=p.v2.z; d[11]=p.v2.w;
                d[12]=p.v3.x; d[13]=p.v3.y; d[14]=p.v3.z; d[15]=p.v3.w;
            }
            // refill the just-consumed buffer with j+2's row
            if (j + 2 < N_J) {
                if (j & 1) issue_gather(pf1, xb, aidx[j + 2], lk);
                else       issue_gather(pf0, xb, aidx[j + 2], lk);
            }

            float s = 0.f;
            #pragma unroll
            for (int i = 0; i < 16; ++i) { d[i] -= ctr[i]; s = fmaf(d[i], d[i], s); }
            // full 64-ch sum: lanes l, l^16, l^32, l^48 hold disjoint channels
            s += __shfl_xor(s, 16);
            s += __shfl_xor(s, 32);
            // frame normalizer: sqrt(sum(diff^2) + norm^2) = sqrt(2)*norm
            const float scale = rsqrtf(2.0f * s);

            bf16x8 bf0, bf1;
            #pragma unroll
            for (int i = 0; i < 8; ++i) {
                bf0[i] = (short)__builtin_bit_cast(unsigned short, __float2bfloat16(d[i]     * scale));
                bf1[i] = (short)__builtin_bit_cast(unsigned short, __float2bfloat16(d[i + 8] * scale));
            }

            // ---- 8 x (2 MFMA): all 128 outputs, A-frags from swizzled LDS ----
            #pragma unroll
            for (int of = 0; of < 8; ++of) {
                const int row = jj * 128 + of * 16 + lrow;
                const bf16x8 a0 = *(const bf16x8*)&buf[(row * 8 + ( lk      ^ sw)) * 8];
                const bf16x8 a1 = *(const bf16x8*)&buf[(row * 8 + ((4 + lk) ^ sw)) * 8];
                f32x4 acc = f32x4{0.f, 0.f, 0.f, 0.f};
                acc = __builtin_amdgcn_mfma_f32_16x16x32_bf16(a0, bf0, acc, 0, 0, 0);
                acc = __builtin_amdgcn_mfma_f32_16x16x32_bf16(a1, bf1, acc, 0, 0, 0);
                #pragma unroll
                for (int r = 0; r < 4; ++r)
                    maxacc[of][r] = fmaxf(maxacc[of][r], acc[r]);   // relu folded
            }
        }

        __syncthreads();            // all waves done reading buf[c&1]
        if (c < 2) {                // async fill chunk c+2 into the freed buffer
            #pragma unroll
            for (int i = 0; i < 8; ++i) {
                const int lo = (w8 * 8 + i) * 512;
                GLOAD(g_wb + (c + 2) * 32768 + lo + lane * 8, &lds_w[c & 1][lo]);
            }
        }
    }

    // ---- store: D row = lk*4 + r, col = lrow (token) ----
    #pragma unroll
    for (int of = 0; of < 8; ++of) {
        const int o0 = of * 16 + lk * 4;
        #pragma unroll
        for (int r = 0; r < 4; ++r)
            ob[(size_t)(o0 + r) * N_PTS + n] = maxacc[of][r];
    }
}

extern "C" void kernel_launch(void* const* d_in, const int* in_sizes, int n_in,
                              void* d_out, int out_size, void* d_ws, size_t ws_size,
                              hipStream_t stream) {
    (void)in_sizes; (void)n_in; (void)d_ws; (void)ws_size; (void)out_size;
    const float* x   = (const float*)d_in[0];
    const int*   adj = (const int*)d_in[1];
    const float* w   = (const float*)d_in[2];
    float*       out = (float*)d_out;

    hipLaunchKernelGGL(prep_weights_k, dim3(512), dim3(256), 0, stream, w);
    hipLaunchKernelGGL(sconv_k,        dim3(256), dim3(512), 0, stream, x, adj, out);
}

// Round 6
// 89.114 us; speedup vs baseline: 1.0132x; 1.0132x over previous
//
#include <hip/hip_runtime.h>
#include <hip/hip_bf16.h>

typedef __attribute__((ext_vector_type(8))) short bf16x8;
typedef __attribute__((ext_vector_type(4))) float f32x4;

#define N_PTS   16384
#define C_CH    64
#define K_ADJ   17
#define C_OUT   128
#define N_J     16

// Weights as a pre-swizzled "LDS image": 4 chunks x 64 KB. Chunk c holds
// j in [c*4, c*4+4). Within a chunk, 16B-slot s: row = s>>3 = (j&3)*128 + o,
// c8 = s&7, and the k-slot group stored there is p8 = c8 ^ (row&7) (XOR bank
// swizzle, T2/m173: swizzle on the SOURCE so a linear global_load_lds DMA
// lands the swizzled layout). k-slot p -> channel permutation matches the
// full-line gather mapping (verified R4/R5: passed, absmax 4.9e-4).
__device__ __hip_bfloat16 g_wb[N_J * C_OUT * C_CH];

__global__ __launch_bounds__(256) void prep_weights_k(const float* __restrict__ w) {
    int idx = blockIdx.x * 256 + threadIdx.x;      // 0 .. 131071 exactly
    int S   = idx >> 3, r = idx & 7;               // 16B slot, element within
    int c   = S >> 12, s = S & 4095;               // chunk, slot in chunk
    int row = s >> 3,  c8 = s & 7;
    int p8  = c8 ^ (row & 7);                      // inverse of read-side XOR
    int j   = c * 4 + (row >> 7);
    int o   = row & 127;
    int p   = p8 * 8 + r;
    int hi  = p >> 5, q = p & 31, la = q >> 3, rr = q & 7;
    int ch  = hi * 32 + (rr < 4 ? la * 4 + rr : 16 + la * 4 + (rr - 4));
    g_wb[idx] = __float2bfloat16(w[(o * C_CH + ch) * (K_ADJ - 1) + j]);
}

#define GLOAD(gp, lp) __builtin_amdgcn_global_load_lds(                       \
    (const __attribute__((address_space(1))) void*)(gp),                      \
    (__attribute__((address_space(3))) void*)(lp), 16, 0, 0)

struct PF { float4 v0, v1, v2, v3; };

__device__ __forceinline__ void issue_gather(PF& p, const float* __restrict__ xb,
                                             int row, int lk) {
    // full-line remap: lane reads 16 contiguous B at row*256 + i*64 + lk*16
    const float* gp = xb + (size_t)row * C_CH + lk * 4;
    p.v0 = *(const float4*)(gp +  0);
    p.v1 = *(const float4*)(gp + 16);
    p.v2 = *(const float4*)(gp + 32);
    p.v3 = *(const float4*)(gp + 48);
}

// Block: 512 threads = 8 waves = 128 tokens; each wave computes all 128
// outputs for its 16 tokens (gathers fully dedup'd). Weights stream through
// 2 x 64KB LDS buffers via async global_load_lds; 4 barriers total.
// Grid 256 = 1 block/CU.
// __launch_bounds__(512, 2): 8-wave block needs exactly 2 waves/EU; raises
// the VGPR cap to 256 (R5's plain (512) capped at 128 -> scratch spills,
// FETCH 27->135 MB).
__global__ __launch_bounds__(512, 2) void sconv_k(
    const float* __restrict__ x,
    const int*   __restrict__ adj,
    float*       __restrict__ out)
{
    __shared__ __hip_bfloat16 lds_w[2][4 * C_OUT * C_CH];   // 2 x 64 KB

    // XCD swizzle (256 blocks): XCDs 0..3 -> batch 0, XCDs 4..7 -> batch 1,
    // so each XCD's 4 MB L2 holds exactly its batch's 4 MB x slice.
    const int pblk = blockIdx.x;
    const int g8   = pblk & 7;
    const int b    = g8 >> 2;
    const int slot = ((pblk >> 3) << 2) | (g8 & 3);          // 0..127 per batch

    const int tid  = threadIdx.x;
    const int lane = tid & 63;
    const int w8   = tid >> 6;                               // wave 0..7
    const int lrow = lane & 15;                              // token in group
    const int lk   = lane >> 4;                              // k-slot group

    const int n = slot * 128 + w8 * 16 + lrow;               // this lane's token

    const float* __restrict__ xb   = x   + (size_t)b * N_PTS * C_CH;
    const int*   __restrict__ adjb = adj + (size_t)b * N_PTS * K_ADJ;
    float*       __restrict__ ob   = out + (size_t)b * C_OUT * N_PTS;

    // ---- async fills for chunks 0 and 1 (issued before everything) ----
    #pragma unroll
    for (int i = 0; i < 8; ++i) {
        const int lo = (w8 * 8 + i) * 512;                   // elements, wave-uniform
        GLOAD(g_wb +         lo + lane * 8, &lds_w[0][lo]);
        GLOAD(g_wb + 32768 + lo + lane * 8, &lds_w[1][lo]);
    }

    // center row (full-line remap: d[i*4+q] = channel i*16 + lk*4 + q)
    float ctr[16];
    {
        const float* rp = xb + (size_t)n * C_CH + lk * 4;
        #pragma unroll
        for (int i = 0; i < 4; ++i) {
            float4 v = *(const float4*)(rp + i * 16);
            ctr[i*4+0]=v.x; ctr[i*4+1]=v.y; ctr[i*4+2]=v.z; ctr[i*4+3]=v.w;
        }
    }

    int aidx[N_J];
    {
        const int base = n * K_ADJ + 1;
        #pragma unroll
        for (int j = 0; j < N_J; ++j) aidx[j] = adjb[base + j];
    }

    f32x4 maxacc[8];
    #pragma unroll
    for (int of = 0; of < 8; ++of) maxacc[of] = f32x4{0.f, 0.f, 0.f, 0.f};

    // gather prefetch depth 2 (named bufs -> all-static indexing, rule #20)
    PF pf0, pf1;
    issue_gather(pf0, xb, aidx[0], lk);
    issue_gather(pf1, xb, aidx[1], lk);

    __syncthreads();   // vmcnt(0)+barrier: chunks 0,1 resident; pf0/pf1 ready

    const int sw = lrow & 7;

    #pragma unroll
    for (int c = 0; c < 4; ++c) {
        const __hip_bfloat16* buf = lds_w[c & 1];

        #pragma unroll
        for (int jj = 0; jj < 4; ++jj) {
            const int j = c * 4 + jj;

            float d[16];
            {
                const PF& p = (j & 1) ? pf1 : pf0;
                d[0] =p.v0.x; d[1] =p.v0.y; d[2] =p.v0.z; d[3] =p.v0.w;
                d[4] =p.v1.x; d[5] =p.v1.y; d[6] =p.v1.z; d[7] =p.v1.w;
                d[8] =p.v2.x; d[9] =p.v2.y; d[10]=p.v2.z; d[11]=p.v2.w;
                d[12]=p.v3.x; d[13]=p.v3.y; d[14]=p.v3.z; d[15]=p.v3.w;
            }
            // refill the just-consumed buffer with j+2's row
            if (j + 2 < N_J) {
                if (j & 1) issue_gather(pf1, xb, aidx[j + 2], lk);
                else       issue_gather(pf0, xb, aidx[j + 2], lk);
            }

            float s = 0.f;
            #pragma unroll
            for (int i = 0; i < 16; ++i) { d[i] -= ctr[i]; s = fmaf(d[i], d[i], s); }
            // full 64-ch sum: lanes l, l^16, l^32, l^48 hold disjoint channels
            s += __shfl_xor(s, 16);
            s += __shfl_xor(s, 32);
            // frame normalizer: sqrt(sum(diff^2) + norm^2) = sqrt(2)*norm
            const float scale = rsqrtf(2.0f * s);

            bf16x8 bf0, bf1;
            #pragma unroll
            for (int i = 0; i < 8; ++i) {
                bf0[i] = (short)__builtin_bit_cast(unsigned short, __float2bfloat16(d[i]     * scale));
                bf1[i] = (short)__builtin_bit_cast(unsigned short, __float2bfloat16(d[i + 8] * scale));
            }

            // ---- 8 x (2 MFMA): all 128 outputs, A-frags from swizzled LDS ----
            #pragma unroll
            for (int of = 0; of < 8; ++of) {
                const int row = jj * 128 + of * 16 + lrow;
                const bf16x8 a0 = *(const bf16x8*)&buf[(row * 8 + ( lk      ^ sw)) * 8];
                const bf16x8 a1 = *(const bf16x8*)&buf[(row * 8 + ((4 + lk) ^ sw)) * 8];
                f32x4 acc = f32x4{0.f, 0.f, 0.f, 0.f};
                acc = __builtin_amdgcn_mfma_f32_16x16x32_bf16(a0, bf0, acc, 0, 0, 0);
                acc = __builtin_amdgcn_mfma_f32_16x16x32_bf16(a1, bf1, acc, 0, 0, 0);
                #pragma unroll
                for (int r = 0; r < 4; ++r)
                    maxacc[of][r] = fmaxf(maxacc[of][r], acc[r]);   // relu folded
            }
        }

        __syncthreads();            // all waves done reading buf[c&1]
        if (c < 2) {                // async fill chunk c+2 into the freed buffer
            #pragma unroll
            for (int i = 0; i < 8; ++i) {
                const int lo = (w8 * 8 + i) * 512;
                GLOAD(g_wb + (c + 2) * 32768 + lo + lane * 8, &lds_w[c & 1][lo]);
            }
        }
    }

    // ---- store: D row = lk*4 + r, col = lrow (token) ----
    #pragma unroll
    for (int of = 0; of < 8; ++of) {
        const int o0 = of * 16 + lk * 4;
        #pragma unroll
        for (int r = 0; r < 4; ++r)
            ob[(size_t)(o0 + r) * N_PTS + n] = maxacc[of][r];
    }
}

extern "C" void kernel_launch(void* const* d_in, const int* in_sizes, int n_in,
                              void* d_out, int out_size, void* d_ws, size_t ws_size,
                              hipStream_t stream) {
    (void)in_sizes; (void)n_in; (void)d_ws; (void)ws_size; (void)out_size;
    const float* x   = (const float*)d_in[0];
    const int*   adj = (const int*)d_in[1];
    const float* w   = (const float*)d_in[2];
    float*       out = (float*)d_out;

    hipLaunchKernelGGL(prep_weights_k, dim3(512), dim3(256), 0, stream, w);
    hipLaunchKernelGGL(sconv_k,        dim3(256), dim3(512), 0, stream, x, adj, out);
}

// Round 8
// 83.092 us; speedup vs baseline: 1.0866x; 1.0725x over previous
//
#include <hip/hip_runtime.h>
#include <hip/hip_bf16.h>

typedef __attribute__((ext_vector_type(8))) short bf16x8;
typedef __attribute__((ext_vector_type(4))) float f32x4;

#define N_PTS   16384
#define C_CH    64
#define K_ADJ   17
#define C_OUT   128
#define N_J     16

// bf16 copy of x: the gather working set. 2 MB per batch -> fits each XCD's
// 4 MB L2 (fp32's 4 MB/batch thrashed: R5/R6 FETCH == full 134 MB gather
// volume at 1.6 TB/s, fabric-bound).
__device__ __align__(16) __hip_bfloat16 g_xb[2 * N_PTS * C_CH];

// Weights as a pre-swizzled LDS image: 4 chunks x 64 KB (4 j per chunk) --
// EXACTLY R6's image, except the k-slot->channel map is identity (bf16
// gather granules are 8 contiguous channels, so the fp32-granule permutation
// collapses). Slot s in chunk: row = s>>3 = (j&3)*128 + o, c8 = s&7; stored
// k-group p8 = c8 ^ (row&7) (XOR swizzle on the SOURCE, m173).
__device__ __align__(16) __hip_bfloat16 g_wb[N_J * C_OUT * C_CH];

__global__ __launch_bounds__(256) void prep_x_k(const float* __restrict__ x) {
    int t = blockIdx.x * 256 + threadIdx.x;        // 0 .. 262143
    const float4 v0 = *(const float4*)(x + t * 8);
    const float4 v1 = *(const float4*)(x + t * 8 + 4);
    bf16x8 o;
    o[0] = (short)__builtin_bit_cast(unsigned short, __float2bfloat16(v0.x));
    o[1] = (short)__builtin_bit_cast(unsigned short, __float2bfloat16(v0.y));
    o[2] = (short)__builtin_bit_cast(unsigned short, __float2bfloat16(v0.z));
    o[3] = (short)__builtin_bit_cast(unsigned short, __float2bfloat16(v0.w));
    o[4] = (short)__builtin_bit_cast(unsigned short, __float2bfloat16(v1.x));
    o[5] = (short)__builtin_bit_cast(unsigned short, __float2bfloat16(v1.y));
    o[6] = (short)__builtin_bit_cast(unsigned short, __float2bfloat16(v1.z));
    o[7] = (short)__builtin_bit_cast(unsigned short, __float2bfloat16(v1.w));
    *(bf16x8*)&g_xb[t * 8] = o;
}

__global__ __launch_bounds__(256) void prep_w_k(const float* __restrict__ w) {
    int idx = blockIdx.x * 256 + threadIdx.x;      // 0 .. 131071 exactly
    int S   = idx >> 3, r = idx & 7;               // 16B slot, elem within
    int c   = S >> 12, s = S & 4095;               // chunk (0..3), slot in chunk
    int row = s >> 3,  c8 = s & 7;
    int p8  = c8 ^ (row & 7);                      // inverse of read-side XOR
    int j   = c * 4 + (row >> 7);
    int o   = row & 127;
    int ch  = p8 * 8 + r;                          // identity k-slot -> channel
    g_wb[idx] = __float2bfloat16(w[(o * C_CH + ch) * (K_ADJ - 1) + j]);
}

#define GLOAD(gp, lp) __builtin_amdgcn_global_load_lds(                       \
    (const __attribute__((address_space(1))) void*)(gp),                      \
    (__attribute__((address_space(3))) void*)(lp), 16, 0, 0)

struct PFB { bf16x8 u0, u1; };

__device__ __forceinline__ void issue_gather(PFB& p, const __hip_bfloat16* __restrict__ xbb,
                                             int row, int lk) {
    // lane (lrow,lk): 16B at channels lk*8+{0..7} and 32+lk*8+{0..7}
    // -> half a 128B row per instr, AND canonical B-frag layout.
    const __hip_bfloat16* gp = xbb + row * C_CH + lk * 8;
    p.u0 = *(const bf16x8*)(gp);
    p.u1 = *(const bf16x8*)(gp + 32);
}

// Block: 512 threads = 8 waves = 128 tokens; each wave computes all 128
// outputs for its 16 tokens (gathers fully dedup'd). Weights stream through
// 2 x 64KB LDS buffers via async global_load_lds; 4 barriers total.
// Grid 256 = 1 block/CU.  (Structure byte-identical to R6, which passed.)
__global__ __launch_bounds__(512, 2) void sconv_k(
    const int* __restrict__ adj,
    float*     __restrict__ out)
{
    __shared__ __hip_bfloat16 lds_w[2][4 * C_OUT * C_CH];   // 2 x 64 KB

    // XCD swizzle (256 blocks): XCDs 0..3 -> batch 0, XCDs 4..7 -> batch 1,
    // so each XCD's L2 holds its batch's 2 MB bf16 x slice.
    const int pblk = blockIdx.x;
    const int g8   = pblk & 7;
    const int b    = g8 >> 2;
    const int slot = ((pblk >> 3) << 2) | (g8 & 3);          // 0..127 per batch

    const int tid  = threadIdx.x;
    const int lane = tid & 63;
    const int w8   = tid >> 6;                               // wave 0..7
    const int lrow = lane & 15;                              // token in group
    const int lk   = lane >> 4;                              // k-slot group

    const int n = slot * 128 + w8 * 16 + lrow;               // this lane's token

    const __hip_bfloat16* __restrict__ xbb = g_xb + b * (N_PTS * C_CH);
    const int* __restrict__ adjb = adj + (size_t)b * N_PTS * K_ADJ;
    float*     __restrict__ ob   = out + (size_t)b * C_OUT * N_PTS;

    // ---- async fills for chunks 0 and 1 (issued before everything) ----
    #pragma unroll
    for (int i = 0; i < 8; ++i) {
        const int lo = (w8 * 8 + i) * 512;                   // wave-uniform elems
        GLOAD(g_wb +         lo + lane * 8, &lds_w[0][lo]);
        GLOAD(g_wb + 32768 + lo + lane * 8, &lds_w[1][lo]);
    }

    // center row (bf16 source, same rounding as gathers)
    float ctr[16];
    {
        const __hip_bfloat16* cp = xbb + n * C_CH + lk * 8;
        const bf16x8 c0 = *(const bf16x8*)(cp);
        const bf16x8 c1 = *(const bf16x8*)(cp + 32);
        #pragma unroll
        for (int i = 0; i < 8; ++i) {
            ctr[i]     = __bfloat162float(__builtin_bit_cast(__hip_bfloat16, (unsigned short)c0[i]));
            ctr[i + 8] = __bfloat162float(__builtin_bit_cast(__hip_bfloat16, (unsigned short)c1[i]));
        }
    }

    int aidx[N_J];
    {
        const int base = n * K_ADJ + 1;
        #pragma unroll
        for (int j = 0; j < N_J; ++j) aidx[j] = adjb[base + j];
    }

    f32x4 maxacc[8];
    #pragma unroll
    for (int of = 0; of < 8; ++of) maxacc[of] = f32x4{0.f, 0.f, 0.f, 0.f};

    // gather prefetch depth 2 (named slots -> static indexing, rule #20)
    PFB pf0, pf1;
    issue_gather(pf0, xbb, aidx[0], lk);
    issue_gather(pf1, xbb, aidx[1], lk);

    __syncthreads();   // vmcnt(0)+barrier: chunks 0,1 resident; pf0/pf1 ready

    const int sw = lrow & 7;

    #pragma unroll
    for (int c = 0; c < 4; ++c) {
        const __hip_bfloat16* buf = lds_w[c & 1];

        #pragma unroll
        for (int jj = 0; jj < 4; ++jj) {
            const int j = c * 4 + jj;

            float d[16];
            {
                const PFB& p = (j & 1) ? pf1 : pf0;
                #pragma unroll
                for (int i = 0; i < 8; ++i) {
                    d[i]     = __bfloat162float(__builtin_bit_cast(__hip_bfloat16, (unsigned short)p.u0[i])) - ctr[i];
                    d[i + 8] = __bfloat162float(__builtin_bit_cast(__hip_bfloat16, (unsigned short)p.u1[i])) - ctr[i + 8];
                }
            }
            // refill the just-consumed slot with j+2's row
            if (j + 2 < N_J) {
                if (j & 1) issue_gather(pf1, xbb, aidx[j + 2], lk);
                else       issue_gather(pf0, xbb, aidx[j + 2], lk);
            }

            float s = 0.f;
            #pragma unroll
            for (int i = 0; i < 16; ++i) s = fmaf(d[i], d[i], s);
            // full 64-ch sum: lanes l, l^16, l^32, l^48 hold disjoint channels
            s += __shfl_xor(s, 16);
            s += __shfl_xor(s, 32);
            // frame normalizer: sqrt(sum(diff^2) + norm^2) = sqrt(2)*norm
            const float scale = rsqrtf(2.0f * s);

            bf16x8 bf0, bf1;
            #pragma unroll
            for (int i = 0; i < 8; ++i) {
                bf0[i] = (short)__builtin_bit_cast(unsigned short, __float2bfloat16(d[i]     * scale));
                bf1[i] = (short)__builtin_bit_cast(unsigned short, __float2bfloat16(d[i + 8] * scale));
            }

            // ---- 8 x (2 MFMA): all 128 outputs, A-frags from swizzled LDS ----
            #pragma unroll
            for (int of = 0; of < 8; ++of) {
                const int row = jj * 128 + of * 16 + lrow;
                const bf16x8 a0 = *(const bf16x8*)&buf[(row * 8 + ( lk      ^ sw)) * 8];
                const bf16x8 a1 = *(const bf16x8*)&buf[(row * 8 + ((4 + lk) ^ sw)) * 8];
                f32x4 acc = f32x4{0.f, 0.f, 0.f, 0.f};
                acc = __builtin_amdgcn_mfma_f32_16x16x32_bf16(a0, bf0, acc, 0, 0, 0);
                acc = __builtin_amdgcn_mfma_f32_16x16x32_bf16(a1, bf1, acc, 0, 0, 0);
                #pragma unroll
                for (int r = 0; r < 4; ++r)
                    maxacc[of][r] = fmaxf(maxacc[of][r], acc[r]);   // relu folded
            }
        }

        __syncthreads();            // all waves done reading buf[c&1]
        if (c < 2) {                // async fill chunk c+2 into the freed buffer
            #pragma unroll
            for (int i = 0; i < 8; ++i) {
                const int lo = (w8 * 8 + i) * 512;
                GLOAD(g_wb + (c + 2) * 32768 + lo + lane * 8, &lds_w[c & 1][lo]);
            }
        }
    }

    // ---- store: D row = lk*4 + r, col = lrow (token) ----
    #pragma unroll
    for (int of = 0; of < 8; ++of) {
        const int o0 = of * 16 + lk * 4;
        #pragma unroll
        for (int r = 0; r < 4; ++r)
            ob[(size_t)(o0 + r) * N_PTS + n] = maxacc[of][r];
    }
}

extern "C" void kernel_launch(void* const* d_in, const int* in_sizes, int n_in,
                              void* d_out, int out_size, void* d_ws, size_t ws_size,
                              hipStream_t stream) {
    (void)in_sizes; (void)n_in; (void)d_ws; (void)ws_size; (void)out_size;
    const float* x   = (const float*)d_in[0];
    const int*   adj = (const int*)d_in[1];
    const float* w   = (const float*)d_in[2];
    float*       out = (float*)d_out;

    hipLaunchKernelGGL(prep_x_k, dim3(1024), dim3(256), 0, stream, x);
    hipLaunchKernelGGL(prep_w_k, dim3(512),  dim3(256), 0, stream, w);
    hipLaunchKernelGGL(sconv_k,  dim3(256),  dim3(512), 0, stream, adj, out);
}